// Round 10
// baseline (729.659 us; speedup 1.0000x reference)
//
#include <hip/hip_runtime.h>

constexpr int BSZ = 8, SEQ = 4096, HID = 1024, NE = 8, CAP = 512;
constexpr int ROWS = BSZ * NE;                          // 64
constexpr size_t IDX_ELEMS = (size_t)ROWS * CAP;        // 32768
constexpr size_t SCR_OFF = IDX_ELEMS;                   // 32768
constexpr size_t MASK_OFF = IDX_ELEMS * 2;              // 65536
constexpr size_t MASK_ELEMS = (size_t)ROWS * CAP * SEQ; // 134217728
constexpr size_t AFF_ELEMS = (size_t)ROWS * SEQ;        // 262144 floats (1 MB)
constexpr size_t AFF_BYTES = AFF_ELEMS * sizeof(float);            // 1 MB
constexpr size_t KEYS_BYTES = (size_t)ROWS * SEQ * 8;              // 2 MB
constexpr size_t WT_BYTES = (size_t)NE * HID * sizeof(float);      // 32 KB

constexpr long long NZ4_TOTAL = (long long)(MASK_ELEMS >> 2);      // 33554432 f4

typedef float f4v __attribute__((ext_vector_type(4)));  // for nontemporal stores

// ---------------------------------------------------------------------------
// Pre-kernel: transpose weight [1024][8] -> wT [8][1024] (32 KB, in d_ws).
// Pure copy; values untouched. 8 blocks x 1024 threads, disjoint writes.
// ---------------------------------------------------------------------------
__global__ void wtranspose_kernel(const float* __restrict__ weight,
                                  float* __restrict__ wT)
{
    const int e = blockIdx.x;       // 0..7
    const int d = threadIdx.x;      // 0..1023
    wT[(size_t)e * HID + d] = weight[(size_t)d * NE + e];
}

// ---------------------------------------------------------------------------
// K0: gating ∥ FULL mask zero (R9-proven plumbing). Gating now reads h and
// wT DIRECTLY from global — no h/w LDS staging, no per-chunk barriers.
// Exact value-substitution vs the absmax=0 kernel:
//   hls[t][x] == hidden[(T0+t)*HID + c*64 + x]
//   wls[e][x] == weight[(c*64+x)*NE + e] == wT[e*HID + c*64 + x]
// Same float4 groups, same 16-float blocks, same chained mul/add order, same
// softmax (lls exchange kept VERBATIM including its barrier).
// ---------------------------------------------------------------------------
__global__ __launch_bounds__(128) void gatezero_kernel(const float* __restrict__ hidden,
                                                       const float* __restrict__ wT,
                                                       float* __restrict__ aff,
                                                       float* __restrict__ out)
{
    __shared__ float lls[16][8];  // logits exchange (ONLY remaining LDS)

    if (blockIdx.x >= 2048) {
        // ---- zero the ENTIRE mask region (no dependence; rides idle write BW)
        f4v* mz = (f4v*)(out + MASK_OFF);
        const f4v z4 = {0.f, 0.f, 0.f, 0.f};
        const long long stride = (long long)(gridDim.x - 2048) * 128;
        for (long long i = (long long)(blockIdx.x - 2048) * 128 + threadIdx.x;
             i < NZ4_TOTAL; i += stride)
            __builtin_nontemporal_store(z4, mz + i);
        return;
    }

    const int tid = threadIdx.x;
    const int T0 = blockIdx.x * 16;
    const int t = tid >> 3;       // token within block
    const int e = tid & 7;        // expert

    const float* __restrict__ hrow = hidden + (size_t)(T0 + t) * HID;
    const float* __restrict__ wrow = wT + (size_t)e * HID;

    float v0 = 0.f, v1 = 0.f, v2 = 0.f, v3 = 0.f; // SSE lanes j=0..3
    for (int c = 0; c < 16; ++c) {
        // four 16-float blocks per chunk, numpy SOP order — values identical
        // to the staged version (see mapping above); no barriers needed.
#pragma unroll
        for (int k = 0; k < 4; ++k) {
            const int base = c * 64 + 16 * k;
            const float4 hA = *(const float4*)(hrow + base + 0);
            const float4 hB = *(const float4*)(hrow + base + 4);
            const float4 hC = *(const float4*)(hrow + base + 8);
            const float4 hD = *(const float4*)(hrow + base + 12);
            const float4 wA = *(const float4*)(wrow + base + 0);
            const float4 wB = *(const float4*)(wrow + base + 4);
            const float4 wC = *(const float4*)(wrow + base + 8);
            const float4 wD = *(const float4*)(wrow + base + 12);
            // v = a0*b0 + (a1*b1 + (a2*b2 + (a3*b3 + v))), per lane, no FMA
            v0 = __fadd_rn(__fmul_rn(hA.x, wA.x),
                 __fadd_rn(__fmul_rn(hB.x, wB.x),
                 __fadd_rn(__fmul_rn(hC.x, wC.x),
                 __fadd_rn(__fmul_rn(hD.x, wD.x), v0))));
            v1 = __fadd_rn(__fmul_rn(hA.y, wA.y),
                 __fadd_rn(__fmul_rn(hB.y, wB.y),
                 __fadd_rn(__fmul_rn(hC.y, wC.y),
                 __fadd_rn(__fmul_rn(hD.y, wD.y), v1))));
            v2 = __fadd_rn(__fmul_rn(hA.z, wA.z),
                 __fadd_rn(__fmul_rn(hB.z, wB.z),
                 __fadd_rn(__fmul_rn(hC.z, wC.z),
                 __fadd_rn(__fmul_rn(hD.z, wD.z), v2))));
            v3 = __fadd_rn(__fmul_rn(hA.w, wA.w),
                 __fadd_rn(__fmul_rn(hB.w, wB.w),
                 __fadd_rn(__fmul_rn(hC.w, wC.w),
                 __fadd_rn(__fmul_rn(hD.w, wD.w), v3))));
        }
    }
    // npyv_sum_f32 with SSE3 (manylinux baseline): double hadd = (v0+v1)+(v2+v3)
    const float logit = __fadd_rn(__fadd_rn(v0, v1), __fadd_rn(v2, v3));

    lls[t][e] = logit;
    __syncthreads();

    float l[8];
#pragma unroll
    for (int k = 0; k < 8; ++k) l[k] = lls[t][k];
    float m = l[0];
#pragma unroll
    for (int k = 1; k < 8; ++k) m = fmaxf(m, l[k]);
    float p[8];
#pragma unroll
    for (int k = 0; k < 8; ++k)
        p[k] = (float)exp((double)__fsub_rn(l[k], m)); // correctly-rounded fp32 exp
    const float s = __fadd_rn(__fadd_rn(__fadd_rn(p[0], p[1]), __fadd_rn(p[2], p[3])),
                              __fadd_rn(__fadd_rn(p[4], p[5]), __fadd_rn(p[6], p[7])));
    const float a = __fdiv_rn(p[e], s);

    const int token = T0 + t;
    const int b = token >> 12;
    const int sidx = token & (SEQ - 1);
    aff[((size_t)b * NE + e) * SEQ + sidx] = a;
}

// ---------------------------------------------------------------------------
// K1: 512 segment-sort blocks — byte-identical to R9 (passed). Keys: R0
// packing (fb<<32)|(SEQ-1-g); all 4096/row unique -> any exact top-512-desc
// algorithm is byte-identical to the verified sort.
// ---------------------------------------------------------------------------
__global__ __launch_bounds__(256) void segsort_kernel(const float* __restrict__ aff,
                                                      unsigned long long* __restrict__ keys)
{
    __shared__ unsigned long long k[512];
    const int row = blockIdx.x >> 3, seg = blockIdx.x & 7;
    const int g0 = seg * 512;
    const float* a = aff + (size_t)row * SEQ + g0;
    for (int j = threadIdx.x; j < 512; j += 256) {
        const unsigned int fb = __float_as_uint(a[j]);
        k[j] = ((unsigned long long)fb << 32) | (unsigned int)(SEQ - 1 - (g0 + j));
    }
    for (int len = 2; len <= 512; len <<= 1) {
        for (int stride = len >> 1; stride > 0; stride >>= 1) {
            __syncthreads();
            const int t = threadIdx.x;                      // exactly 256 CEs
            const int i = (t << 1) - (t & (stride - 1));
            const int j = i + stride;
            const unsigned long long ki = k[i], kj = k[j];
            const bool desc = ((i & len) == 0);
            if (desc ? (ki < kj) : (ki > kj)) { k[i] = kj; k[j] = ki; }
        }
    }
    __syncthreads();
    unsigned long long* dst = keys + (size_t)row * SEQ + g0;
    for (int j = threadIdx.x; j < 512; j += 256) dst[j] = k[j];
}

// ---------------------------------------------------------------------------
// K2: per-row merge (bitonic half-cleaner prune + 9-pass desc cleanup) +
// indices/scores + one-hot scatter — byte-identical to R9 (passed).
// ---------------------------------------------------------------------------
__global__ __launch_bounds__(512) void merge_scatter_kernel(const unsigned long long* __restrict__ keys,
                                                            float* __restrict__ out)
{
    __shared__ unsigned long long A[SEQ]; // 32 KB
    const int row = blockIdx.x;
    for (int i = threadIdx.x; i < SEQ; i += 512)
        A[i] = keys[(size_t)row * SEQ + i];

    for (int round = 0; round < 3; ++round) {
        const int sp = 1024 << round;        // pair span: 1024,2048,4096
        const int npairs = 4 >> round;       // 4,2,1
        __syncthreads();
        // prune pass: survivors at bases p*sp, partners at base+sp/2
        for (int u = threadIdx.x; u < npairs * 512; u += 512) {
            const int p = u >> 9, i = u & 511;
            const int base = p * sp;
            const unsigned long long x = A[base + i];
            const unsigned long long y = A[base + sp / 2 + 511 - i];
            if (y > x) A[base + i] = y;      // keep max in front half
        }
        // desc bitonic cleanup of each surviving (bitonic) 512-run
        for (int s = 256; s > 0; s >>= 1) {
            __syncthreads();
            for (int u = threadIdx.x; u < npairs * 256; u += 512) {
                const int r = u >> 8, t2 = u & 255;
                const int base = r * sp;
                const int i = (t2 << 1) - (t2 & (s - 1));
                const unsigned long long x = A[base + i], y = A[base + i + s];
                if (y > x) { A[base + i] = y; A[base + i + s] = x; }
            }
        }
    }
    __syncthreads();
    if (threadIdx.x < CAP) {
        const int t = threadIdx.x;
        const unsigned long long k = A[t];
        const int idx = (SEQ - 1) - (int)(unsigned int)(k & 0xffffffffu);
        out[(size_t)row * CAP + t] = (float)idx;                      // indices
        out[SCR_OFF + (size_t)row * CAP + t] =
            __uint_as_float((unsigned int)(k >> 32));                 // scores
        out[MASK_OFF + ((size_t)row * CAP + t) * SEQ + idx] = 1.0f;   // one-hot
    }
}

// ---------------------------------------------------------------------------
// Fallback gating (aff-only), original single-buffered LDS version — frozen.
// ---------------------------------------------------------------------------
__global__ __launch_bounds__(128) void gating_kernel(const float* __restrict__ hidden,
                                                     const float* __restrict__ weight,
                                                     float* __restrict__ aff)
{
    __shared__ float hls[16][68];
    __shared__ float wls[8][68];
    __shared__ float lls[16][8];

    const int tid = threadIdx.x;
    const int T0 = blockIdx.x * 16;
    const int t = tid >> 3;
    const int e = tid & 7;

    float v0 = 0.f, v1 = 0.f, v2 = 0.f, v3 = 0.f;
    for (int c = 0; c < 16; ++c) {
        __syncthreads();
#pragma unroll
        for (int k = 0; k < 2; ++k) {
            const int j = tid + k * 128;
            const int tt = j >> 4, q = j & 15;
            const float4 v = *(const float4*)(hidden + (size_t)(T0 + tt) * HID + c * 64 + 4 * q);
            *(float4*)&hls[tt][4 * q] = v;
        }
#pragma unroll
        for (int k = 0; k < 4; ++k) {
            const int j = tid + k * 128;
            const int dd = j >> 3, ee = j & 7;
            wls[ee][dd] = weight[(size_t)(c * 64 + dd) * NE + ee];
        }
        __syncthreads();
#pragma unroll
        for (int k = 0; k < 4; ++k) {
            const int base = 16 * k;
            const float4 hA = *(const float4*)&hls[t][base + 0];
            const float4 hB = *(const float4*)&hls[t][base + 4];
            const float4 hC = *(const float4*)&hls[t][base + 8];
            const float4 hD = *(const float4*)&hls[t][base + 12];
            const float4 wA = *(const float4*)&wls[e][base + 0];
            const float4 wB = *(const float4*)&wls[e][base + 4];
            const float4 wC = *(const float4*)&wls[e][base + 8];
            const float4 wD = *(const float4*)&wls[e][base + 12];
            v0 = __fadd_rn(__fmul_rn(hA.x, wA.x),
                 __fadd_rn(__fmul_rn(hB.x, wB.x),
                 __fadd_rn(__fmul_rn(hC.x, wC.x),
                 __fadd_rn(__fmul_rn(hD.x, wD.x), v0))));
            v1 = __fadd_rn(__fmul_rn(hA.y, wA.y),
                 __fadd_rn(__fmul_rn(hB.y, wB.y),
                 __fadd_rn(__fmul_rn(hC.y, wC.y),
                 __fadd_rn(__fmul_rn(hD.y, wD.y), v1))));
            v2 = __fadd_rn(__fmul_rn(hA.z, wA.z),
                 __fadd_rn(__fmul_rn(hB.z, wB.z),
                 __fadd_rn(__fmul_rn(hC.z, wC.z),
                 __fadd_rn(__fmul_rn(hD.z, wD.z), v2))));
            v3 = __fadd_rn(__fmul_rn(hA.w, wA.w),
                 __fadd_rn(__fmul_rn(hB.w, wB.w),
                 __fadd_rn(__fmul_rn(hC.w, wC.w),
                 __fadd_rn(__fmul_rn(hD.w, wD.w), v3))));
        }
    }
    const float logit = __fadd_rn(__fadd_rn(v0, v1), __fadd_rn(v2, v3));

    lls[t][e] = logit;
    __syncthreads();

    float l[8];
#pragma unroll
    for (int k = 0; k < 8; ++k) l[k] = lls[t][k];
    float m = l[0];
#pragma unroll
    for (int k = 1; k < 8; ++k) m = fmaxf(m, l[k]);
    float p[8];
#pragma unroll
    for (int k = 0; k < 8; ++k)
        p[k] = (float)exp((double)__fsub_rn(l[k], m));
    const float s = __fadd_rn(__fadd_rn(__fadd_rn(p[0], p[1]), __fadd_rn(p[2], p[3])),
                              __fadd_rn(__fadd_rn(p[4], p[5]), __fadd_rn(p[6], p[7])));
    const float a = __fdiv_rn(p[e], s);

    const int token = T0 + t;
    const int b = token >> 12;
    const int sidx = token & (SEQ - 1);
    aff[((size_t)b * NE + e) * SEQ + sidx] = a;
}

// ---------------------------------------------------------------------------
// Fallback 1 (1MB <= ws < fast): R4's proven fused per-row kernel.
// ---------------------------------------------------------------------------
__global__ __launch_bounds__(1024) void sortzero_kernel(const float* __restrict__ aff,
                                                        float* __restrict__ out)
{
    __shared__ unsigned long long keys[SEQ]; // 32 KB
    const int row = blockIdx.x;
    const float* a = aff + (size_t)row * SEQ;
    float* mrow = out + MASK_OFF + (size_t)row * CAP * SEQ;

    for (int i = threadIdx.x; i < SEQ; i += 1024) {
        const unsigned int fb = __float_as_uint(a[i]);
        keys[i] = ((unsigned long long)fb << 32) | (unsigned int)(SEQ - 1 - i);
    }
    f4v* mz = (f4v*)mrow;
    const f4v z4 = {0.f, 0.f, 0.f, 0.f};
    int zi = 0;
    for (int len = 2; len <= SEQ; len <<= 1) {
        for (int stride = len >> 1; stride > 0; stride >>= 1) {
            __syncthreads();
#pragma unroll
            for (int k = 0; k < 7; ++k) {
                if (zi < 512) {
                    __builtin_nontemporal_store(z4, mz + (size_t)zi * 1024 + threadIdx.x);
                    ++zi;
                }
            }
            for (int t = threadIdx.x; t < SEQ / 2; t += 1024) {
                const int i = (t << 1) - (t & (stride - 1));
                const int j = i + stride;
                const unsigned long long ki = keys[i], kj = keys[j];
                const bool desc = ((i & len) == 0);
                if (desc ? (ki < kj) : (ki > kj)) { keys[i] = kj; keys[j] = ki; }
            }
        }
    }
    __syncthreads();
    if (threadIdx.x < CAP) {
        const int t = threadIdx.x;
        const unsigned long long k = keys[t];
        const int idx = (SEQ - 1) - (int)(unsigned int)(k & 0xffffffffu);
        out[(size_t)row * CAP + t] = (float)idx;
        out[SCR_OFF + (size_t)row * CAP + t] =
            __uint_as_float((unsigned int)(k >> 32));
        mrow[(size_t)t * SEQ + idx] = 1.0f;
    }
}

// ---------------------------------------------------------------------------
// Fallback 2 (ws < 1MB): R3 borrow-tail path, byte-identical behavior.
// ---------------------------------------------------------------------------
__global__ __launch_bounds__(1024) void topk_zero_kernel(const float* __restrict__ aff,
                                                         float* __restrict__ out,
                                                         long long zero_elems)
{
    __shared__ unsigned long long keys[SEQ];
    if (blockIdx.x < (unsigned)ROWS) {
        const int row = blockIdx.x;
        const float* a = aff + (size_t)row * SEQ;
        for (int i = threadIdx.x; i < SEQ; i += 1024) {
            const unsigned int fb = __float_as_uint(a[i]);
            keys[i] = ((unsigned long long)fb << 32) | (unsigned int)(SEQ - 1 - i);
        }
        for (int len = 2; len <= SEQ; len <<= 1) {
            for (int stride = len >> 1; stride > 0; stride >>= 1) {
                __syncthreads();
                for (int t = threadIdx.x; t < SEQ / 2; t += 1024) {
                    const int i = (t << 1) - (t & (stride - 1));
                    const int j = i + stride;
                    const unsigned long long ki = keys[i], kj = keys[j];
                    const bool desc = ((i & len) == 0);
                    if (desc ? (ki < kj) : (ki > kj)) { keys[i] = kj; keys[j] = ki; }
                }
            }
        }
        __syncthreads();
        if (threadIdx.x < CAP) {
            const int t = threadIdx.x;
            const unsigned long long k = keys[t];
            const int idx = (SEQ - 1) - (int)(unsigned int)(k & 0xffffffffu);
            out[(size_t)row * CAP + t] = (float)idx;
            out[SCR_OFF + (size_t)row * CAP + t] =
                __uint_as_float((unsigned int)(k >> 32));
        }
    } else {
        const long long nz4 = zero_elems >> 2;
        f4v* mz = (f4v*)(out + MASK_OFF);
        const f4v z4 = {0.f, 0.f, 0.f, 0.f};
        const long long stride = (long long)(gridDim.x - ROWS) * 1024;
        for (long long i = (long long)(blockIdx.x - ROWS) * 1024 + threadIdx.x;
             i < nz4; i += stride)
            __builtin_nontemporal_store(z4, mz + i);
    }
}

__global__ void tailzero_kernel(float* __restrict__ out)
{
    const long long n4 = (long long)(AFF_ELEMS >> 2);
    f4v* mz = (f4v*)(out + MASK_OFF + MASK_ELEMS - AFF_ELEMS);
    const f4v z4 = {0.f, 0.f, 0.f, 0.f};
    const long long i = (long long)blockIdx.x * blockDim.x + threadIdx.x;
    if (i < n4) __builtin_nontemporal_store(z4, mz + i);
}

__global__ void scatter_kernel(float* __restrict__ out)
{
    const int p = blockIdx.x * blockDim.x + threadIdx.x;
    if (p < (int)IDX_ELEMS) {
        const int idx = (int)out[p];
        out[MASK_OFF + (size_t)p * SEQ + idx] = 1.0f;
    }
}

extern "C" void kernel_launch(void* const* d_in, const int* in_sizes, int n_in,
                              void* d_out, int out_size, void* d_ws, size_t ws_size,
                              hipStream_t stream)
{
    const float* hidden = (const float*)d_in[0];
    const float* weight = (const float*)d_in[1];
    float* out = (float*)d_out;

    if (ws_size >= AFF_BYTES + KEYS_BYTES + WT_BYTES) {
        // Fast path: wT transpose -> (global-read gating ∥ FULL zero)
        //            -> segsort -> merge+scatter.
        float* aff = (float*)d_ws;
        unsigned long long* keys = (unsigned long long*)((char*)d_ws + AFF_BYTES);
        float* wT = (float*)((char*)d_ws + AFF_BYTES + KEYS_BYTES);
        wtranspose_kernel<<<NE, HID, 0, stream>>>(weight, wT);
        gatezero_kernel<<<2048 + 1920, 128, 0, stream>>>(hidden, wT, aff, out);
        segsort_kernel<<<512, 256, 0, stream>>>(aff, keys);
        merge_scatter_kernel<<<ROWS, 512, 0, stream>>>(keys, out);
    } else if (ws_size >= AFF_BYTES) {
        // R4 proven path.
        float* aff = (float*)d_ws;
        gating_kernel<<<2048, 128, 0, stream>>>(hidden, weight, aff);
        sortzero_kernel<<<ROWS, 1024, 0, stream>>>(aff, out);
    } else {
        // R3 proven borrow-tail path.
        float* aff = out + MASK_OFF + MASK_ELEMS - AFF_ELEMS;
        gating_kernel<<<2048, 128, 0, stream>>>(hidden, weight, aff);
        const long long zero_elems = (long long)(MASK_ELEMS - AFF_ELEMS);
        topk_zero_kernel<<<ROWS + 1984, 1024, 0, stream>>>(aff, out, zero_elems);
        tailzero_kernel<<<256, 256, 0, stream>>>(out);
        scatter_kernel<<<(int)((IDX_ELEMS + 255) / 256), 256, 0, stream>>>(out);
    }
}

// Round 11
// 636.875 us; speedup vs baseline: 1.1457x; 1.1457x over previous
//
#include <hip/hip_runtime.h>

constexpr int BSZ = 8, SEQ = 4096, HID = 1024, NE = 8, CAP = 512;
constexpr int ROWS = BSZ * NE;                          // 64
constexpr size_t IDX_ELEMS = (size_t)ROWS * CAP;        // 32768
constexpr size_t SCR_OFF = IDX_ELEMS;                   // 32768
constexpr size_t MASK_OFF = IDX_ELEMS * 2;              // 65536
constexpr size_t MASK_ELEMS = (size_t)ROWS * CAP * SEQ; // 134217728
constexpr size_t AFF_ELEMS = (size_t)ROWS * SEQ;        // 262144 floats (1 MB)
constexpr size_t AFF_BYTES = AFF_ELEMS * sizeof(float);            // 1 MB

constexpr long long NZ4_TOTAL = (long long)(MASK_ELEMS >> 2);      // 33554432 f4
constexpr long long Z_SPLIT   = NZ4_TOTAL * 5 / 8;                 // 62.5% in K0

typedef float f4v __attribute__((ext_vector_type(4)));  // for nontemporal stores

// ---------------------------------------------------------------------------
// K0: gating ∥ zero-part-A — VERBATIM the R6/R9 kernel that passed (gating
// body frozen; zero-A covers the first 62.5% as in R6's best-measured run).
// ---------------------------------------------------------------------------
__global__ __launch_bounds__(128) void gatezero_kernel(const float* __restrict__ hidden,
                                                       const float* __restrict__ weight,
                                                       float* __restrict__ aff,
                                                       float* __restrict__ out)
{
    __shared__ float hls[16][68]; // 16 tokens x 64-d chunk (pad to 68)
    __shared__ float wls[8][68];  // transposed weight chunk: [e][dd]
    __shared__ float lls[16][8];  // logits exchange

    if (blockIdx.x >= 2048) {
        // ---- zero-part-A: [0, Z_SPLIT) ----
        f4v* mz = (f4v*)(out + MASK_OFF);
        const f4v z4 = {0.f, 0.f, 0.f, 0.f};
        const long long stride = (long long)(gridDim.x - 2048) * 128;
        for (long long i = (long long)(blockIdx.x - 2048) * 128 + threadIdx.x;
             i < Z_SPLIT; i += stride)
            __builtin_nontemporal_store(z4, mz + i);
        return;
    }

    // ---- gating: DO NOT TOUCH (byte-identical to the absmax=0 kernel) ----
    const int tid = threadIdx.x;
    const int T0 = blockIdx.x * 16;
    const int t = tid >> 3;       // token within block
    const int e = tid & 7;        // expert

    float v0 = 0.f, v1 = 0.f, v2 = 0.f, v3 = 0.f; // SSE lanes j=0..3
    for (int c = 0; c < 16; ++c) {
        __syncthreads(); // protect previous chunk's reads
        // stage hidden chunk: 256 float4s, coalesced
#pragma unroll
        for (int k = 0; k < 2; ++k) {
            const int j = tid + k * 128;      // 0..255
            const int tt = j >> 4, q = j & 15;
            const float4 v = *(const float4*)(hidden + (size_t)(T0 + tt) * HID + c * 64 + 4 * q);
            *(float4*)&hls[tt][4 * q] = v;
        }
        // stage weight chunk transposed: 512 scalars, coalesced global reads
#pragma unroll
        for (int k = 0; k < 4; ++k) {
            const int j = tid + k * 128;      // 0..511 == dd*8+ee
            const int dd = j >> 3, ee = j & 7;
            wls[ee][dd] = weight[(size_t)(c * 64 + dd) * NE + ee];
        }
        __syncthreads();
        // four 16-float blocks per chunk, numpy SOP order
#pragma unroll
        for (int k = 0; k < 4; ++k) {
            const int base = 16 * k;
            const float4 hA = *(const float4*)&hls[t][base + 0];
            const float4 hB = *(const float4*)&hls[t][base + 4];
            const float4 hC = *(const float4*)&hls[t][base + 8];
            const float4 hD = *(const float4*)&hls[t][base + 12];
            const float4 wA = *(const float4*)&wls[e][base + 0];
            const float4 wB = *(const float4*)&wls[e][base + 4];
            const float4 wC = *(const float4*)&wls[e][base + 8];
            const float4 wD = *(const float4*)&wls[e][base + 12];
            // v = a0*b0 + (a1*b1 + (a2*b2 + (a3*b3 + v))), per lane, no FMA
            v0 = __fadd_rn(__fmul_rn(hA.x, wA.x),
                 __fadd_rn(__fmul_rn(hB.x, wB.x),
                 __fadd_rn(__fmul_rn(hC.x, wC.x),
                 __fadd_rn(__fmul_rn(hD.x, wD.x), v0))));
            v1 = __fadd_rn(__fmul_rn(hA.y, wA.y),
                 __fadd_rn(__fmul_rn(hB.y, wB.y),
                 __fadd_rn(__fmul_rn(hC.y, wC.y),
                 __fadd_rn(__fmul_rn(hD.y, wD.y), v1))));
            v2 = __fadd_rn(__fmul_rn(hA.z, wA.z),
                 __fadd_rn(__fmul_rn(hB.z, wB.z),
                 __fadd_rn(__fmul_rn(hC.z, wC.z),
                 __fadd_rn(__fmul_rn(hD.z, wD.z), v2))));
            v3 = __fadd_rn(__fmul_rn(hA.w, wA.w),
                 __fadd_rn(__fmul_rn(hB.w, wB.w),
                 __fadd_rn(__fmul_rn(hC.w, wC.w),
                 __fadd_rn(__fmul_rn(hD.w, wD.w), v3))));
        }
    }
    // npyv_sum_f32 with SSE3 (manylinux baseline): double hadd = (v0+v1)+(v2+v3)
    const float logit = __fadd_rn(__fadd_rn(v0, v1), __fadd_rn(v2, v3));

    lls[t][e] = logit;
    __syncthreads();

    float l[8];
#pragma unroll
    for (int k = 0; k < 8; ++k) l[k] = lls[t][k];
    float m = l[0];
#pragma unroll
    for (int k = 1; k < 8; ++k) m = fmaxf(m, l[k]);
    float p[8];
#pragma unroll
    for (int k = 0; k < 8; ++k)
        p[k] = (float)exp((double)__fsub_rn(l[k], m)); // correctly-rounded fp32 exp
    const float s = __fadd_rn(__fadd_rn(__fadd_rn(p[0], p[1]), __fadd_rn(p[2], p[3])),
                              __fadd_rn(__fadd_rn(p[4], p[5]), __fadd_rn(p[6], p[7])));
    const float a = __fdiv_rn(p[e], s);

    const int token = T0 + t;
    const int b = token >> 12;
    const int sidx = token & (SEQ - 1);
    aff[((size_t)b * NE + e) * SEQ + sidx] = a;
}

// ---------------------------------------------------------------------------
// K1': fused per-row {8-segment parallel bitonic sort + merge + indices/
// scores} (blocks 0..63) ∥ zero-part-B (blocks >= 64). Sort: the SAME CE
// sequence as the proven segsort (8 segments, disjoint pairs per pass, local
// index governs direction) — only intra-pass scheduling differs, which is
// value-neutral. Merge rounds + epilogue copied VERBATIM from the proven
// merge_scatter_kernel, minus the mask scatter (moved to K2 so it runs after
// ALL zeroing, exactly like R6's ordering).
// ---------------------------------------------------------------------------
__global__ __launch_bounds__(512) void sortmerge_zero_kernel(const float* __restrict__ aff,
                                                             float* __restrict__ out)
{
    __shared__ unsigned long long A[SEQ]; // 32 KB
    if (blockIdx.x < (unsigned)ROWS) {
        const int row = blockIdx.x;
        const float* a = aff + (size_t)row * SEQ;
        for (int i = threadIdx.x; i < SEQ; i += 512) {
            const unsigned int fb = __float_as_uint(a[i]);
            A[i] = ((unsigned long long)fb << 32) | (unsigned int)(SEQ - 1 - i);
        }
        // 8 segments of 512, sorted descending with the proven CE sequence.
        for (int len = 2; len <= 512; len <<= 1) {
            for (int stride = len >> 1; stride > 0; stride >>= 1) {
                __syncthreads();
                for (int u = threadIdx.x; u < 2048; u += 512) {
                    const int seg = u >> 8, t2 = u & 255;
                    const int i = (t2 << 1) - (t2 & (stride - 1)); // local idx
                    const int gi = seg * 512 + i, gj = gi + stride;
                    const unsigned long long ki = A[gi], kj = A[gj];
                    const bool desc = ((i & len) == 0);
                    if (desc ? (ki < kj) : (ki > kj)) { A[gi] = kj; A[gj] = ki; }
                }
            }
        }
        // merge rounds — verbatim from the proven merge_scatter_kernel
        for (int round = 0; round < 3; ++round) {
            const int sp = 1024 << round;        // pair span: 1024,2048,4096
            const int npairs = 4 >> round;       // 4,2,1
            __syncthreads();
            for (int u = threadIdx.x; u < npairs * 512; u += 512) {
                const int p = u >> 9, i = u & 511;
                const int base = p * sp;
                const unsigned long long x = A[base + i];
                const unsigned long long y = A[base + sp / 2 + 511 - i];
                if (y > x) A[base + i] = y;      // keep max in front half
            }
            for (int s = 256; s > 0; s >>= 1) {
                __syncthreads();
                for (int u = threadIdx.x; u < npairs * 256; u += 512) {
                    const int r = u >> 8, t2 = u & 255;
                    const int base = r * sp;
                    const int i = (t2 << 1) - (t2 & (s - 1));
                    const unsigned long long x = A[base + i], y = A[base + i + s];
                    if (y > x) { A[base + i] = y; A[base + i + s] = x; }
                }
            }
        }
        __syncthreads();
        if (threadIdx.x < CAP) {
            const int t = threadIdx.x;
            const unsigned long long k = A[t];
            const int idx = (SEQ - 1) - (int)(unsigned int)(k & 0xffffffffu);
            out[(size_t)row * CAP + t] = (float)idx;                      // indices
            out[SCR_OFF + (size_t)row * CAP + t] =
                __uint_as_float((unsigned int)(k >> 32));                 // scores
        }
    } else {
        // ---- zero-part-B: [Z_SPLIT, NZ4_TOTAL) ----
        f4v* mz = (f4v*)(out + MASK_OFF);
        const f4v z4 = {0.f, 0.f, 0.f, 0.f};
        const long long stride = (long long)(gridDim.x - ROWS) * 512;
        for (long long i = Z_SPLIT + (long long)(blockIdx.x - ROWS) * 512 + threadIdx.x;
             i < NZ4_TOTAL; i += stride)
            __builtin_nontemporal_store(z4, mz + i);
    }
}

// ---------------------------------------------------------------------------
// K2: scatter the one-hot ones — VERBATIM the R0-proven kernel; runs after
// all zeroing (stream order).
// ---------------------------------------------------------------------------
__global__ void scatter_kernel(float* __restrict__ out)
{
    const int p = blockIdx.x * blockDim.x + threadIdx.x;
    if (p < (int)IDX_ELEMS) {
        const int idx = (int)out[p];
        out[MASK_OFF + (size_t)p * SEQ + idx] = 1.0f;
    }
}

// ---------------------------------------------------------------------------
// Fallback gating (aff-only), frozen original — used by the borrow-tail path.
// ---------------------------------------------------------------------------
__global__ __launch_bounds__(128) void gating_kernel(const float* __restrict__ hidden,
                                                     const float* __restrict__ weight,
                                                     float* __restrict__ aff)
{
    __shared__ float hls[16][68];
    __shared__ float wls[8][68];
    __shared__ float lls[16][8];

    const int tid = threadIdx.x;
    const int T0 = blockIdx.x * 16;
    const int t = tid >> 3;
    const int e = tid & 7;

    float v0 = 0.f, v1 = 0.f, v2 = 0.f, v3 = 0.f;
    for (int c = 0; c < 16; ++c) {
        __syncthreads();
#pragma unroll
        for (int k = 0; k < 2; ++k) {
            const int j = tid + k * 128;
            const int tt = j >> 4, q = j & 15;
            const float4 v = *(const float4*)(hidden + (size_t)(T0 + tt) * HID + c * 64 + 4 * q);
            *(float4*)&hls[tt][4 * q] = v;
        }
#pragma unroll
        for (int k = 0; k < 4; ++k) {
            const int j = tid + k * 128;
            const int dd = j >> 3, ee = j & 7;
            wls[ee][dd] = weight[(size_t)(c * 64 + dd) * NE + ee];
        }
        __syncthreads();
#pragma unroll
        for (int k = 0; k < 4; ++k) {
            const int base = 16 * k;
            const float4 hA = *(const float4*)&hls[t][base + 0];
            const float4 hB = *(const float4*)&hls[t][base + 4];
            const float4 hC = *(const float4*)&hls[t][base + 8];
            const float4 hD = *(const float4*)&hls[t][base + 12];
            const float4 wA = *(const float4*)&wls[e][base + 0];
            const float4 wB = *(const float4*)&wls[e][base + 4];
            const float4 wC = *(const float4*)&wls[e][base + 8];
            const float4 wD = *(const float4*)&wls[e][base + 12];
            v0 = __fadd_rn(__fmul_rn(hA.x, wA.x),
                 __fadd_rn(__fmul_rn(hB.x, wB.x),
                 __fadd_rn(__fmul_rn(hC.x, wC.x),
                 __fadd_rn(__fmul_rn(hD.x, wD.x), v0))));
            v1 = __fadd_rn(__fmul_rn(hA.y, wA.y),
                 __fadd_rn(__fmul_rn(hB.y, wB.y),
                 __fadd_rn(__fmul_rn(hC.y, wC.y),
                 __fadd_rn(__fmul_rn(hD.y, wD.y), v1))));
            v2 = __fadd_rn(__fmul_rn(hA.z, wA.z),
                 __fadd_rn(__fmul_rn(hB.z, wB.z),
                 __fadd_rn(__fmul_rn(hC.z, wC.z),
                 __fadd_rn(__fmul_rn(hD.z, wD.z), v2))));
            v3 = __fadd_rn(__fmul_rn(hA.w, wA.w),
                 __fadd_rn(__fmul_rn(hB.w, wB.w),
                 __fadd_rn(__fmul_rn(hC.w, wC.w),
                 __fadd_rn(__fmul_rn(hD.w, wD.w), v3))));
        }
    }
    const float logit = __fadd_rn(__fadd_rn(v0, v1), __fadd_rn(v2, v3));

    lls[t][e] = logit;
    __syncthreads();

    float l[8];
#pragma unroll
    for (int k = 0; k < 8; ++k) l[k] = lls[t][k];
    float m = l[0];
#pragma unroll
    for (int k = 1; k < 8; ++k) m = fmaxf(m, l[k]);
    float p[8];
#pragma unroll
    for (int k = 0; k < 8; ++k)
        p[k] = (float)exp((double)__fsub_rn(l[k], m));
    const float s = __fadd_rn(__fadd_rn(__fadd_rn(p[0], p[1]), __fadd_rn(p[2], p[3])),
                              __fadd_rn(__fadd_rn(p[4], p[5]), __fadd_rn(p[6], p[7])));
    const float a = __fdiv_rn(p[e], s);

    const int token = T0 + t;
    const int b = token >> 12;
    const int sidx = token & (SEQ - 1);
    aff[((size_t)b * NE + e) * SEQ + sidx] = a;
}

// ---------------------------------------------------------------------------
// Fallback (ws < 1MB): R3 borrow-tail path, byte-identical behavior.
// ---------------------------------------------------------------------------
__global__ __launch_bounds__(1024) void topk_zero_kernel(const float* __restrict__ aff,
                                                         float* __restrict__ out,
                                                         long long zero_elems)
{
    __shared__ unsigned long long keys[SEQ];
    if (blockIdx.x < (unsigned)ROWS) {
        const int row = blockIdx.x;
        const float* a = aff + (size_t)row * SEQ;
        for (int i = threadIdx.x; i < SEQ; i += 1024) {
            const unsigned int fb = __float_as_uint(a[i]);
            keys[i] = ((unsigned long long)fb << 32) | (unsigned int)(SEQ - 1 - i);
        }
        for (int len = 2; len <= SEQ; len <<= 1) {
            for (int stride = len >> 1; stride > 0; stride >>= 1) {
                __syncthreads();
                for (int t = threadIdx.x; t < SEQ / 2; t += 1024) {
                    const int i = (t << 1) - (t & (stride - 1));
                    const int j = i + stride;
                    const unsigned long long ki = keys[i], kj = keys[j];
                    const bool desc = ((i & len) == 0);
                    if (desc ? (ki < kj) : (ki > kj)) { keys[i] = kj; keys[j] = ki; }
                }
            }
        }
        __syncthreads();
        if (threadIdx.x < CAP) {
            const int t = threadIdx.x;
            const unsigned long long k = keys[t];
            const int idx = (SEQ - 1) - (int)(unsigned int)(k & 0xffffffffu);
            out[(size_t)row * CAP + t] = (float)idx;
            out[SCR_OFF + (size_t)row * CAP + t] =
                __uint_as_float((unsigned int)(k >> 32));
        }
    } else {
        const long long nz4 = zero_elems >> 2;
        f4v* mz = (f4v*)(out + MASK_OFF);
        const f4v z4 = {0.f, 0.f, 0.f, 0.f};
        const long long stride = (long long)(gridDim.x - ROWS) * 1024;
        for (long long i = (long long)(blockIdx.x - ROWS) * 1024 + threadIdx.x;
             i < nz4; i += stride)
            __builtin_nontemporal_store(z4, mz + i);
    }
}

__global__ void tailzero_kernel(float* __restrict__ out)
{
    const long long n4 = (long long)(AFF_ELEMS >> 2);
    f4v* mz = (f4v*)(out + MASK_OFF + MASK_ELEMS - AFF_ELEMS);
    const f4v z4 = {0.f, 0.f, 0.f, 0.f};
    const long long i = (long long)blockIdx.x * blockDim.x + threadIdx.x;
    if (i < n4) __builtin_nontemporal_store(z4, mz + i);
}

extern "C" void kernel_launch(void* const* d_in, const int* in_sizes, int n_in,
                              void* d_out, int out_size, void* d_ws, size_t ws_size,
                              hipStream_t stream)
{
    const float* hidden = (const float*)d_in[0];
    const float* weight = (const float*)d_in[1];
    float* out = (float*)d_out;

    if (ws_size >= AFF_BYTES) {
        // Fast path: (gating ∥ zero-A) -> (sort+merge ∥ zero-B) -> scatter.
        float* aff = (float*)d_ws;
        gatezero_kernel<<<2048 + 1920, 128, 0, stream>>>(hidden, weight, aff, out);
        sortmerge_zero_kernel<<<ROWS + 960, 512, 0, stream>>>(aff, out);
        scatter_kernel<<<(int)((IDX_ELEMS + 255) / 256), 256, 0, stream>>>(out);
    } else {
        // R3 proven borrow-tail path.
        float* aff = out + MASK_OFF + MASK_ELEMS - AFF_ELEMS;
        gating_kernel<<<2048, 128, 0, stream>>>(hidden, weight, aff);
        const long long zero_elems = (long long)(MASK_ELEMS - AFF_ELEMS);
        topk_zero_kernel<<<ROWS + 1984, 1024, 0, stream>>>(aff, out, zero_elems);
        tailzero_kernel<<<256, 256, 0, stream>>>(out);
        scatter_kernel<<<(int)((IDX_ELEMS + 255) / 256), 256, 0, stream>>>(out);
    }
}